// Round 15
// baseline (81.949 us; speedup 1.0000x reference)
//
#include <hip/hip_runtime.h>
#include <hip/hip_bf16.h>

// ---------------- types ----------------
typedef __bf16 bf16x8 __attribute__((ext_vector_type(8)));
typedef float  f32x4  __attribute__((ext_vector_type(4)));
typedef unsigned short u16x8 __attribute__((ext_vector_type(8)));

#define NTOK 16384      // B*S
#define SEQ  4096
#define DIM  128
#define NSEG 13         // 1 g-segment + 12 f-segments
#define NM   12
#define NK   13

// round-to-nearest-even f32 -> bf16 bits
__device__ inline unsigned short f2bf(float f) {
    unsigned int u = __float_as_uint(f);
    unsigned int r = (u + 0x7FFFu + ((u >> 16) & 1u)) >> 16;
    return (unsigned short)r;
}
__device__ inline float bf2f(unsigned short h) {
    return __uint_as_float(((unsigned int)h) << 16);
}
__device__ inline float uaf(unsigned int u) { return __uint_as_float(u); }
// packed f32x2 -> bf16x2 (lo=a, hi=b), RNE (same as f2bf)
__device__ inline unsigned int cvtpk(float a, float b) {
    unsigned int r;
    asm("v_cvt_pk_bf16_f32 %0, %1, %2" : "=v"(r) : "v"(a), "v"(b));
    return r;
}

// 5-op gelu, CORRECT small-|u| form (leading correction is QUADRATIC):
//   gelu(u) = 0.5u + u^2*(c0 + u^2*c1 + u^4*c2),  c0=0.5*sqrt(2/pi), c1=-c0/6, c2=c0/40
__device__ inline float gelu_f(float u) {
    const float c0 = 0.3989422804f;
    const float c1 = -0.0664903801f;
    const float c2 = 0.0099735570f;
    float u2 = u * u;
    float p  = __builtin_fmaf(u2, c2, c1);
    p        = __builtin_fmaf(u2, p, c0);
    return __builtin_fmaf(u2, p, 0.5f * u);
}

// LDS XOR-swizzle: rows are 256B (128 u16). XOR byte bits [4:6] with row bits [8:10].
__device__ inline int swz(int u16idx) {
    int byte = u16idx << 1;
    byte ^= ((byte >> 8) & 7) << 4;
    return byte >> 1;
}

// ---------------- kernel 1: fused embed (x = emb[data]+apc -> bf16) + weight conv ----------------
#define EMB_BLOCKS 8192                         // 2 rows per 256-thread block
#define CONV_BLOCKS ((NSEG * DIM * DIM + 255) / 256)
__global__ __launch_bounds__(256) void prep_kernel(
    const int* __restrict__ data, const float* __restrict__ emb,
    const float* __restrict__ apc, unsigned short* __restrict__ xb,
    const float* __restrict__ g_W1, const float* __restrict__ g_W2,
    const float* __restrict__ f_W1, const float* __restrict__ f_W2,
    unsigned short* __restrict__ wb1T, unsigned short* __restrict__ wb2Tg,
    unsigned short* __restrict__ wb2Tf)
{
    int tid = threadIdx.x;
    if (blockIdx.x < EMB_BLOCKS) {
        int n = blockIdx.x * 2 + (tid >> 7);
        int d = tid & 127;
        int s = n & (SEQ - 1);
        int tok = data[n];
        float v = emb[(size_t)tok * DIM + d] + apc[s * DIM + d];
        xb[(size_t)n * DIM + d] = f2bf(v);
    } else {
        int i = (blockIdx.x - EMB_BLOCKS) * 256 + tid;
        if (i < NSEG * DIM * DIM) {
            int seg = i >> 14;
            int e = (i >> 7) & 127;
            int d = i & 127;
            float v = (seg == 0) ? g_W1[d * DIM + e]
                                 : f_W1[((seg - 1) * DIM + d) * DIM + e];
            wb1T[i] = f2bf(v);
        }
        if (i < DIM * DIM) {
            int c = i >> 7, e = i & 127;
            wb2Tg[i] = f2bf(g_W2[e * DIM + c]);
        }
        if (i < NM * 16 * DIM) {
            int m = i >> 11;
            int c = (i >> 7) & 15;
            int e = i & 127;
            float v = (c < NK) ? f_W2[(m * DIM + e) * NK + c] : 0.f;
            wb2Tf[i] = f2bf(v);
        }
    }
}

// ---------------- kernel 2: fused MLP — W in LDS (reused 32x), X direct from global ----------------
__global__ __launch_bounds__(256, 3) void mlp_kernel(
    const unsigned short* __restrict__ xb,
    const unsigned short* __restrict__ wb1T,
    const unsigned short* __restrict__ wb2Tg,
    const unsigned short* __restrict__ wb2Tf,
    const float* __restrict__ g_b1, const float* __restrict__ g_b2,
    const float* __restrict__ f_b1, const float* __restrict__ f_b2,
    float* __restrict__ resF, unsigned short* __restrict__ resB,
    unsigned short* __restrict__ Wallb)
{
    const int seg  = blockIdx.y;           // 0 => g ; 1..12 => f[seg-1]
    const int row0 = blockIdx.x * 64;
    const int tid  = threadIdx.x;
    const int wave = tid >> 6;             // 0..3
    const int lane = tid & 63;

    __shared__ __align__(16) unsigned short Hs[4][16 * DIM];  // 16 KB wave-private strips
    __shared__ __align__(16) unsigned short W1s[DIM * DIM];   // 32 KB
    __shared__ __align__(16) unsigned short W2fs[16 * DIM];   // 4 KB

    const int r16   = lane & 15;
    const int kgrp  = (lane >> 4) * 8;
    const int crow0 = (lane >> 4) << 2;    // strip-local C row base

    // biases into registers (overlaps staging)
    const float* b1p = (seg == 0) ? g_b1 : (f_b1 + (seg - 1) * DIM);
    float bias1[8];
    #pragma unroll
    for (int t = 0; t < 8; ++t) bias1[t] = b1p[t * 16 + r16];
    float bias2[8];
    float bias2f = 0.f;
    if (seg == 0) {
        #pragma unroll
        for (int t = 0; t < 8; ++t) bias2[t] = g_b2[t * 16 + r16];
    } else {
        bias2f = (r16 < NK) ? f_b2[(seg - 1) * NK + r16] : 0.f;
    }

    // stage W1T (128x128) swizzled
    {
        const int4* wg = reinterpret_cast<const int4*>(wb1T + (size_t)seg * DIM * DIM);
        #pragma unroll
        for (int i = 0; i < 8; ++i)
            *reinterpret_cast<int4*>(&W1s[swz((tid + i * 256) * 8)]) = wg[tid + i * 256];
    }
    // stage W2f (16x128) swizzled — f-segments only
    if (seg != 0) {
        const int4* wg = reinterpret_cast<const int4*>(wb2Tf + (size_t)(seg - 1) * 16 * DIM);
        *reinterpret_cast<int4*>(&W2fs[swz(tid * 8)]) = wg[tid];
    }
    __syncthreads();   // the ONLY barrier (waits on W staging only)

    // ---- layer 1: acc = X @ W1 ; A direct from global, B from LDS ----
    const unsigned short* xrow = xb + (size_t)(row0 + wave * 16 + r16) * DIM + kgrp;
    f32x4 acc[8];
    #pragma unroll
    for (int t = 0; t < 8; ++t) acc[t] = (f32x4){0.f, 0.f, 0.f, 0.f};
    #pragma unroll
    for (int kk = 0; kk < 4; ++kk) {
        bf16x8 a = *reinterpret_cast<const bf16x8*>(xrow + kk * 32);
        #pragma unroll
        for (int t = 0; t < 8; ++t) {
            bf16x8 b = *reinterpret_cast<const bf16x8*>(&W1s[swz((t * 16 + r16) * DIM + kk * 32 + kgrp)]);
            acc[t] = __builtin_amdgcn_mfma_f32_16x16x32_bf16(a, b, acc[t], 0, 0, 0);
        }
    }

    // ---- gelu -> H into this wave's own swizzled strip (cvt_pk pairs) ----
    unsigned short* hs = Hs[wave];
    #pragma unroll
    for (int t = 0; t < 8; ++t) {
        int col = t * 16 + r16;
        #pragma unroll
        for (int r = 0; r < 4; r += 2) {
            float g0 = gelu_f(acc[t][r]     + bias1[t]);
            float g1 = gelu_f(acc[t][r + 1] + bias1[t]);
            unsigned int pk = cvtpk(g0, g1);
            hs[swz((crow0 + r)     * DIM + col)] = (unsigned short)pk;
            hs[swz((crow0 + r + 1) * DIM + col)] = (unsigned short)(pk >> 16);
        }
    }

    // ---- layer 2 ----
    if (seg == 0) {
        f32x4 acc2[8];
        #pragma unroll
        for (int t = 0; t < 8; ++t) acc2[t] = (f32x4){0.f, 0.f, 0.f, 0.f};
        #pragma unroll
        for (int kk = 0; kk < 4; ++kk) {
            bf16x8 a = *reinterpret_cast<const bf16x8*>(&hs[swz(r16 * DIM + kk * 32 + kgrp)]);
            #pragma unroll
            for (int t = 0; t < 8; ++t) {
                bf16x8 b = *reinterpret_cast<const bf16x8*>(wb2Tg + (size_t)(t * 16 + r16) * DIM + kk * 32 + kgrp);
                acc2[t] = __builtin_amdgcn_mfma_f32_16x16x32_bf16(a, b, acc2[t], 0, 0, 0);
            }
        }
        #pragma unroll
        for (int t = 0; t < 8; ++t) {
            int col = t * 16 + r16;
            #pragma unroll
            for (int r = 0; r < 4; r += 2) {
                int grow = row0 + wave * 16 + crow0 + r;
                float v0 = acc2[t][r]     + bias2[t];
                float v1 = acc2[t][r + 1] + bias2[t];
                resF[(size_t)grow * DIM + col]       = v0;
                resF[(size_t)(grow + 1) * DIM + col] = v1;
                unsigned int pk = cvtpk(v0, v1);
                resB[(size_t)grow * DIM + col]       = (unsigned short)pk;
                resB[(size_t)(grow + 1) * DIM + col] = (unsigned short)(pk >> 16);
            }
        }
    } else {
        int m = seg - 1;
        f32x4 acc2 = (f32x4){0.f, 0.f, 0.f, 0.f};
        #pragma unroll
        for (int kk = 0; kk < 4; ++kk) {
            bf16x8 a = *reinterpret_cast<const bf16x8*>(&hs[swz(r16 * DIM + kk * 32 + kgrp)]);
            bf16x8 b = *reinterpret_cast<const bf16x8*>(&W2fs[swz(r16 * DIM + kk * 32 + kgrp)]);
            acc2 = __builtin_amdgcn_mfma_f32_16x16x32_bf16(a, b, acc2, 0, 0, 0);
        }
        #pragma unroll
        for (int r = 0; r < 4; r += 2) {
            int grow = row0 + wave * 16 + crow0 + r;
            unsigned int pk = cvtpk(acc2[r] + bias2f, acc2[r + 1] + bias2f);
            Wallb[((size_t)m * NTOK + grow) * 16 + r16]     = (unsigned short)pk;
            Wallb[((size_t)m * NTOK + grow + 1) * 16 + r16] = (unsigned short)(pk >> 16);
        }
    }
}

// ---------------- kernel 3: ALL 12 scan steps — token-pair ds_read_b64 gathers ----------------
// Thread owns token pairs A=(2tid, 2tid+1), B=(2048+2tid, 2048+2tid+1). LDS word u = token u
// (2 bf16 channels). One aligned b64 read serves BOTH pair tokens for every even offset
// (off=2..512, 1024); off=1 resolves to own-register + the off=2 read; off=0/2048 are the
// A<->B register swap. DS ops/thread/step: 45 -> 23 (8B/lane stride: conflict-free).
// B-pair's off=1024 wrap is a step-invariant precomputed address; ring pad stays 512 words.
// Numerics bit-identical: ascending-k FMA chain per token, RNE cvtpk carry, bf16 res
// steps 0..10, f32 resF + f32 out at step 11.
#define CCH 2
#define RPAD 512
#define WTOT (SEQ + RPAD)               // 4608 words per buffer; 2 buffers = 36 KB
__global__ __launch_bounds__(1024) void scan_lds_kernel(
    const unsigned short* __restrict__ resB,
    const float* __restrict__ resF,
    const unsigned short* __restrict__ Wallb,   // [NM][NTOK][16]
    float* __restrict__ outF)
{
    __shared__ __align__(16) unsigned int V32[2 * WTOT];   // 36 KB

    const int bid = (int)blockIdx.x;
    const int bb    = (bid >> 1) & 3;                 // batch -> XCD pair
    const int chunk = ((bid >> 3) << 1) | (bid & 1);  // 0..63
    const int d0  = chunk * CCH;
    const int tid = threadIdx.x;                      // 0..1023
    const int t2  = tid * 2;                          // A0 token
    const int b10off = (t2 < 1024) ? (3072 + t2) : (t2 - 1024);  // B-pair off-1024 base (wrapped)

    // ---- one-time: res words + own-V pairs + seed V0 (with ring pad) ----
    uint2 resA, resBw, BvA, BvB;
    {
        const size_t nA0 = (size_t)((bb << 12) + t2);
        unsigned int a0 = *reinterpret_cast<const unsigned int*>(resB + nA0 * DIM + d0);
        unsigned int a1 = *reinterpret_cast<const unsigned int*>(resB + (nA0 + 1) * DIM + d0);
        unsigned int b0 = *reinterpret_cast<const unsigned int*>(resB + (nA0 + 2048) * DIM + d0);
        unsigned int b1 = *reinterpret_cast<const unsigned int*>(resB + (nA0 + 2049) * DIM + d0);
        resA = make_uint2(a0, a1);
        resBw = make_uint2(b0, b1);
        BvA = resA; BvB = resBw;
        *reinterpret_cast<uint2*>(&V32[t2]) = resA;
        *reinterpret_cast<uint2*>(&V32[2048 + t2]) = resBw;
        if (t2 < RPAD) *reinterpret_cast<uint2*>(&V32[SEQ + t2]) = resA;
    }
    const unsigned short* wb0 = Wallb + (size_t)(bb << 12) * 16;
    __syncthreads();

    unsigned int cur = 0;

    // ---- steps 0..10: bf16 V carry ----
    #pragma unroll 1
    for (int m = 0; m < NM - 1; ++m) {
        const unsigned short* wp = wb0 + (size_t)m * NTOK * 16;

        // W rows for the 4 owned tokens (7 useful dwords each; rows A0/A1 and B0/B1 contiguous)
        unsigned int w[4][7];
        #pragma unroll
        for (int jj = 0; jj < 4; ++jj) {
            const int row = (jj < 2) ? (t2 + jj) : (2048 + t2 + (jj - 2));
            const unsigned int* wr = reinterpret_cast<const unsigned int*>(wp + (size_t)row * 16);
            uint4 a = *reinterpret_cast<const uint4*>(wr);
            uint2 b = *reinterpret_cast<const uint2*>(wr + 4);
            w[jj][0] = a.x; w[jj][1] = a.y; w[jj][2] = a.z; w[jj][3] = a.w;
            w[jj][4] = b.x; w[jj][5] = b.y; w[jj][6] = wr[6];
        }

        // 20 b64 LDS reads: pair taps for off = 2..512 (q=1..9) and off = 1024
        uint2 pA[9], pB[9];
        #pragma unroll
        for (int q = 1; q <= 9; ++q) {
            pA[q - 1] = *reinterpret_cast<const uint2*>(&V32[cur + t2 + (1 << q)]);
            pB[q - 1] = *reinterpret_cast<const uint2*>(&V32[cur + 2048 + t2 + (1 << q)]);
        }
        uint2 pA10 = *reinterpret_cast<const uint2*>(&V32[cur + t2 + 1024]);
        uint2 pB10 = *reinterpret_cast<const uint2*>(&V32[cur + b10off]);
        __builtin_amdgcn_sched_barrier(0);   // pin: no sinking reads into the FMA chain

        float oL[4], oH[4];
        oL[0] = uaf(resA.x << 16);  oH[0] = uaf(resA.x & 0xffff0000u);
        oL[1] = uaf(resA.y << 16);  oH[1] = uaf(resA.y & 0xffff0000u);
        oL[2] = uaf(resBw.x << 16); oH[2] = uaf(resBw.x & 0xffff0000u);
        oL[3] = uaf(resBw.y << 16); oH[3] = uaf(resBw.y & 0xffff0000u);

        #pragma unroll
        for (int k = 0; k < NK; ++k) {
            unsigned int v0, v1, v2, v3;   // tap words for tokens A0, A1, B0, B1
            if (k == 0)       { v0 = BvA.x;        v1 = BvA.y;        v2 = BvB.x;        v3 = BvB.y; }
            else if (k == 1)  { v0 = BvA.y;        v1 = pA[0].x;      v2 = BvB.y;        v3 = pB[0].x; }
            else if (k <= 10) { v0 = pA[k - 2].x;  v1 = pA[k - 2].y;  v2 = pB[k - 2].x;  v3 = pB[k - 2].y; }
            else if (k == 11) { v0 = pA10.x;       v1 = pA10.y;       v2 = pB10.x;       v3 = pB10.y; }
            else              { v0 = BvB.x;        v1 = BvB.y;        v2 = BvA.x;        v3 = BvA.y; }
            #pragma unroll
            for (int jj = 0; jj < 4; ++jj) {
                unsigned int ww = w[jj][k >> 1];
                float wv = (k & 1) ? uaf(ww & 0xffff0000u) : uaf(ww << 16);
                unsigned int v = (jj == 0) ? v0 : (jj == 1) ? v1 : (jj == 2) ? v2 : v3;
                oL[jj] = __builtin_fmaf(wv, uaf(v << 16),          oL[jj]);
                oH[jj] = __builtin_fmaf(wv, uaf(v & 0xffff0000u), oH[jj]);
            }
        }

        const unsigned int nb = cur ^ WTOT;
        uint2 wa, wbv;
        wa.x  = cvtpk(oL[0], oH[0]);  wa.y  = cvtpk(oL[1], oH[1]);
        wbv.x = cvtpk(oL[2], oH[2]);  wbv.y = cvtpk(oL[3], oH[3]);
        BvA = wa; BvB = wbv;
        *reinterpret_cast<uint2*>(&V32[nb + t2]) = wa;
        *reinterpret_cast<uint2*>(&V32[nb + 2048 + t2]) = wbv;
        if (t2 < RPAD) *reinterpret_cast<uint2*>(&V32[nb + SEQ + t2]) = wa;
        __syncthreads();
        cur = nb;
    }

    // ---- final step m=11: f32 res, f32 out ----
    {
        const unsigned short* wp = wb0 + (size_t)(NM - 1) * NTOK * 16;
        const size_t nA0 = (size_t)((bb << 12) + t2);

        float2 rf[4];
        rf[0] = *reinterpret_cast<const float2*>(resF + nA0 * DIM + d0);
        rf[1] = *reinterpret_cast<const float2*>(resF + (nA0 + 1) * DIM + d0);
        rf[2] = *reinterpret_cast<const float2*>(resF + (nA0 + 2048) * DIM + d0);
        rf[3] = *reinterpret_cast<const float2*>(resF + (nA0 + 2049) * DIM + d0);

        unsigned int w[4][7];
        #pragma unroll
        for (int jj = 0; jj < 4; ++jj) {
            const int row = (jj < 2) ? (t2 + jj) : (2048 + t2 + (jj - 2));
            const unsigned int* wr = reinterpret_cast<const unsigned int*>(wp + (size_t)row * 16);
            uint4 a = *reinterpret_cast<const uint4*>(wr);
            uint2 b = *reinterpret_cast<const uint2*>(wr + 4);
            w[jj][0] = a.x; w[jj][1] = a.y; w[jj][2] = a.z; w[jj][3] = a.w;
            w[jj][4] = b.x; w[jj][5] = b.y; w[jj][6] = wr[6];
        }

        uint2 pA[9], pB[9];
        #pragma unroll
        for (int q = 1; q <= 9; ++q) {
            pA[q - 1] = *reinterpret_cast<const uint2*>(&V32[cur + t2 + (1 << q)]);
            pB[q - 1] = *reinterpret_cast<const uint2*>(&V32[cur + 2048 + t2 + (1 << q)]);
        }
        uint2 pA10 = *reinterpret_cast<const uint2*>(&V32[cur + t2 + 1024]);
        uint2 pB10 = *reinterpret_cast<const uint2*>(&V32[cur + b10off]);
        __builtin_amdgcn_sched_barrier(0);

        float oL[4], oH[4];
        #pragma unroll
        for (int jj = 0; jj < 4; ++jj) { oL[jj] = rf[jj].x; oH[jj] = rf[jj].y; }

        #pragma unroll
        for (int k = 0; k < NK; ++k) {
            unsigned int v0, v1, v2, v3;
            if (k == 0)       { v0 = BvA.x;        v1 = BvA.y;        v2 = BvB.x;        v3 = BvB.y; }
            else if (k == 1)  { v0 = BvA.y;        v1 = pA[0].x;      v2 = BvB.y;        v3 = pB[0].x; }
            else if (k <= 10) { v0 = pA[k - 2].x;  v1 = pA[k - 2].y;  v2 = pB[k - 2].x;  v3 = pB[k - 2].y; }
            else if (k == 11) { v0 = pA10.x;       v1 = pA10.y;       v2 = pB10.x;       v3 = pB10.y; }
            else              { v0 = BvB.x;        v1 = BvB.y;        v2 = BvA.x;        v3 = BvA.y; }
            #pragma unroll
            for (int jj = 0; jj < 4; ++jj) {
                unsigned int ww = w[jj][k >> 1];
                float wv = (k & 1) ? uaf(ww & 0xffff0000u) : uaf(ww << 16);
                unsigned int v = (jj == 0) ? v0 : (jj == 1) ? v1 : (jj == 2) ? v2 : v3;
                oL[jj] = __builtin_fmaf(wv, uaf(v << 16),          oL[jj]);
                oH[jj] = __builtin_fmaf(wv, uaf(v & 0xffff0000u), oH[jj]);
            }
        }

        float2 o;
        o.x = oL[0]; o.y = oH[0];
        *reinterpret_cast<float2*>(outF + nA0 * DIM + d0) = o;
        o.x = oL[1]; o.y = oH[1];
        *reinterpret_cast<float2*>(outF + (nA0 + 1) * DIM + d0) = o;
        o.x = oL[2]; o.y = oH[2];
        *reinterpret_cast<float2*>(outF + (nA0 + 2048) * DIM + d0) = o;
        o.x = oL[3]; o.y = oH[3];
        *reinterpret_cast<float2*>(outF + (nA0 + 2049) * DIM + d0) = o;
    }
}

// ---------------- launch ----------------
extern "C" void kernel_launch(void* const* d_in, const int* in_sizes, int n_in,
                              void* d_out, int out_size, void* d_ws, size_t ws_size,
                              hipStream_t stream) {
    const int*   data = (const int*)  d_in[0];
    const float* emb  = (const float*)d_in[2];
    const float* apc  = (const float*)d_in[3];
    const float* g_W1 = (const float*)d_in[4];
    const float* g_b1 = (const float*)d_in[5];
    const float* g_W2 = (const float*)d_in[6];
    const float* g_b2 = (const float*)d_in[7];
    const float* f_W1 = (const float*)d_in[8];
    const float* f_b1 = (const float*)d_in[9];
    const float* f_W2 = (const float*)d_in[10];
    const float* f_b2 = (const float*)d_in[11];
    float* out = (float*)d_out;

    char* ws = (char*)d_ws;
    size_t off = 0;
    auto alloc = [&](size_t bytes) {
        void* p = ws + off;
        off += (bytes + 255) & ~(size_t)255;
        return p;
    };
    unsigned short* xb    = (unsigned short*)alloc((size_t)NTOK * DIM * 2);
    unsigned short* wb1T  = (unsigned short*)alloc((size_t)NSEG * DIM * DIM * 2);
    unsigned short* wb2Tg = (unsigned short*)alloc((size_t)DIM * DIM * 2);
    unsigned short* wb2Tf = (unsigned short*)alloc((size_t)NM * 16 * DIM * 2);
    float*          resF  = (float*)alloc((size_t)NTOK * DIM * 4);
    unsigned short* resB  = (unsigned short*)alloc((size_t)NTOK * DIM * 2);
    unsigned short* Wallb = (unsigned short*)alloc((size_t)NM * NTOK * 16 * 2);
    (void)ws_size; (void)in_sizes; (void)n_in; (void)out_size;

    prep_kernel<<<EMB_BLOCKS + CONV_BLOCKS, 256, 0, stream>>>(
        data, emb, apc, xb, g_W1, g_W2, f_W1, f_W2, wb1T, wb2Tg, wb2Tf);

    dim3 grid(NTOK / 64, NSEG);
    mlp_kernel<<<grid, 256, 0, stream>>>(xb, wb1T, wb2Tg, wb2Tf,
                                         g_b1, g_b2, f_b1, f_b2, resF, resB, Wallb);

    // all 12 scan steps in one kernel: token-pair b64 LDS gathers (23 DS ops/thread/step),
    // sched_barrier-pinned read batches, batch->XCD pinned
    scan_lds_kernel<<<256, 1024, 0, stream>>>(resB, resF, Wallb, out);
}

// Round 16
// 73.259 us; speedup vs baseline: 1.1186x; 1.1186x over previous
//
#include <hip/hip_runtime.h>
#include <hip/hip_bf16.h>

// ---------------- types ----------------
typedef __bf16 bf16x8 __attribute__((ext_vector_type(8)));
typedef float  f32x4  __attribute__((ext_vector_type(4)));
typedef unsigned short u16x8 __attribute__((ext_vector_type(8)));

#define NTOK 16384      // B*S
#define SEQ  4096
#define DIM  128
#define NSEG 13         // 1 g-segment + 12 f-segments
#define NM   12
#define NK   13

// round-to-nearest-even f32 -> bf16 bits
__device__ inline unsigned short f2bf(float f) {
    unsigned int u = __float_as_uint(f);
    unsigned int r = (u + 0x7FFFu + ((u >> 16) & 1u)) >> 16;
    return (unsigned short)r;
}
__device__ inline float bf2f(unsigned short h) {
    return __uint_as_float(((unsigned int)h) << 16);
}
__device__ inline float uaf(unsigned int u) { return __uint_as_float(u); }
// packed f32x2 -> bf16x2 (lo=a, hi=b), RNE (same as f2bf)
__device__ inline unsigned int cvtpk(float a, float b) {
    unsigned int r;
    asm("v_cvt_pk_bf16_f32 %0, %1, %2" : "=v"(r) : "v"(a), "v"(b));
    return r;
}

// 5-op gelu, CORRECT small-|u| form (leading correction is QUADRATIC):
//   gelu(u) = 0.5u + u^2*(c0 + u^2*c1 + u^4*c2),  c0=0.5*sqrt(2/pi), c1=-c0/6, c2=c0/40
__device__ inline float gelu_f(float u) {
    const float c0 = 0.3989422804f;
    const float c1 = -0.0664903801f;
    const float c2 = 0.0099735570f;
    float u2 = u * u;
    float p  = __builtin_fmaf(u2, c2, c1);
    p        = __builtin_fmaf(u2, p, c0);
    return __builtin_fmaf(u2, p, 0.5f * u);
}

// LDS XOR-swizzle: rows are 256B (128 u16). XOR byte bits [4:6] with row bits [8:10].
__device__ inline int swz(int u16idx) {
    int byte = u16idx << 1;
    byte ^= ((byte >> 8) & 7) << 4;
    return byte >> 1;
}

// ---------------- kernel 1: fused embed (x = emb[data]+apc -> bf16) + weight conv ----------------
#define EMB_BLOCKS 8192                         // 2 rows per 256-thread block
#define CONV_BLOCKS ((NSEG * DIM * DIM + 255) / 256)
__global__ __launch_bounds__(256) void prep_kernel(
    const int* __restrict__ data, const float* __restrict__ emb,
    const float* __restrict__ apc, unsigned short* __restrict__ xb,
    const float* __restrict__ g_W1, const float* __restrict__ g_W2,
    const float* __restrict__ f_W1, const float* __restrict__ f_W2,
    unsigned short* __restrict__ wb1T, unsigned short* __restrict__ wb2Tg,
    unsigned short* __restrict__ wb2Tf)
{
    int tid = threadIdx.x;
    if (blockIdx.x < EMB_BLOCKS) {
        int n = blockIdx.x * 2 + (tid >> 7);
        int d = tid & 127;
        int s = n & (SEQ - 1);
        int tok = data[n];
        float v = emb[(size_t)tok * DIM + d] + apc[s * DIM + d];
        xb[(size_t)n * DIM + d] = f2bf(v);
    } else {
        int i = (blockIdx.x - EMB_BLOCKS) * 256 + tid;
        if (i < NSEG * DIM * DIM) {
            int seg = i >> 14;
            int e = (i >> 7) & 127;
            int d = i & 127;
            float v = (seg == 0) ? g_W1[d * DIM + e]
                                 : f_W1[((seg - 1) * DIM + d) * DIM + e];
            wb1T[i] = f2bf(v);
        }
        if (i < DIM * DIM) {
            int c = i >> 7, e = i & 127;
            wb2Tg[i] = f2bf(g_W2[e * DIM + c]);
        }
        if (i < NM * 16 * DIM) {
            int m = i >> 11;
            int c = (i >> 7) & 15;
            int e = i & 127;
            float v = (c < NK) ? f_W2[(m * DIM + e) * NK + c] : 0.f;
            wb2Tf[i] = f2bf(v);
        }
    }
}

// ---------------- kernel 2: fused MLP — W in LDS (reused 32x), X direct from global ----------------
__global__ __launch_bounds__(256, 3) void mlp_kernel(
    const unsigned short* __restrict__ xb,
    const unsigned short* __restrict__ wb1T,
    const unsigned short* __restrict__ wb2Tg,
    const unsigned short* __restrict__ wb2Tf,
    const float* __restrict__ g_b1, const float* __restrict__ g_b2,
    const float* __restrict__ f_b1, const float* __restrict__ f_b2,
    float* __restrict__ resF, unsigned short* __restrict__ resB,
    unsigned short* __restrict__ Wallb)
{
    const int seg  = blockIdx.y;           // 0 => g ; 1..12 => f[seg-1]
    const int row0 = blockIdx.x * 64;
    const int tid  = threadIdx.x;
    const int wave = tid >> 6;             // 0..3
    const int lane = tid & 63;

    __shared__ __align__(16) unsigned short Hs[4][16 * DIM];  // 16 KB wave-private strips
    __shared__ __align__(16) unsigned short W1s[DIM * DIM];   // 32 KB
    __shared__ __align__(16) unsigned short W2fs[16 * DIM];   // 4 KB

    const int r16   = lane & 15;
    const int kgrp  = (lane >> 4) * 8;
    const int crow0 = (lane >> 4) << 2;    // strip-local C row base

    // biases into registers (overlaps staging)
    const float* b1p = (seg == 0) ? g_b1 : (f_b1 + (seg - 1) * DIM);
    float bias1[8];
    #pragma unroll
    for (int t = 0; t < 8; ++t) bias1[t] = b1p[t * 16 + r16];
    float bias2[8];
    float bias2f = 0.f;
    if (seg == 0) {
        #pragma unroll
        for (int t = 0; t < 8; ++t) bias2[t] = g_b2[t * 16 + r16];
    } else {
        bias2f = (r16 < NK) ? f_b2[(seg - 1) * NK + r16] : 0.f;
    }

    // stage W1T (128x128) swizzled
    {
        const int4* wg = reinterpret_cast<const int4*>(wb1T + (size_t)seg * DIM * DIM);
        #pragma unroll
        for (int i = 0; i < 8; ++i)
            *reinterpret_cast<int4*>(&W1s[swz((tid + i * 256) * 8)]) = wg[tid + i * 256];
    }
    // stage W2f (16x128) swizzled — f-segments only
    if (seg != 0) {
        const int4* wg = reinterpret_cast<const int4*>(wb2Tf + (size_t)(seg - 1) * 16 * DIM);
        *reinterpret_cast<int4*>(&W2fs[swz(tid * 8)]) = wg[tid];
    }
    __syncthreads();   // the ONLY barrier (waits on W staging only)

    // ---- layer 1: acc = X @ W1 ; A direct from global, B from LDS ----
    const unsigned short* xrow = xb + (size_t)(row0 + wave * 16 + r16) * DIM + kgrp;
    f32x4 acc[8];
    #pragma unroll
    for (int t = 0; t < 8; ++t) acc[t] = (f32x4){0.f, 0.f, 0.f, 0.f};
    #pragma unroll
    for (int kk = 0; kk < 4; ++kk) {
        bf16x8 a = *reinterpret_cast<const bf16x8*>(xrow + kk * 32);
        #pragma unroll
        for (int t = 0; t < 8; ++t) {
            bf16x8 b = *reinterpret_cast<const bf16x8*>(&W1s[swz((t * 16 + r16) * DIM + kk * 32 + kgrp)]);
            acc[t] = __builtin_amdgcn_mfma_f32_16x16x32_bf16(a, b, acc[t], 0, 0, 0);
        }
    }

    // ---- gelu -> H into this wave's own swizzled strip (cvt_pk pairs) ----
    unsigned short* hs = Hs[wave];
    #pragma unroll
    for (int t = 0; t < 8; ++t) {
        int col = t * 16 + r16;
        #pragma unroll
        for (int r = 0; r < 4; r += 2) {
            float g0 = gelu_f(acc[t][r]     + bias1[t]);
            float g1 = gelu_f(acc[t][r + 1] + bias1[t]);
            unsigned int pk = cvtpk(g0, g1);
            hs[swz((crow0 + r)     * DIM + col)] = (unsigned short)pk;
            hs[swz((crow0 + r + 1) * DIM + col)] = (unsigned short)(pk >> 16);
        }
    }

    // ---- layer 2 ----
    if (seg == 0) {
        f32x4 acc2[8];
        #pragma unroll
        for (int t = 0; t < 8; ++t) acc2[t] = (f32x4){0.f, 0.f, 0.f, 0.f};
        #pragma unroll
        for (int kk = 0; kk < 4; ++kk) {
            bf16x8 a = *reinterpret_cast<const bf16x8*>(&hs[swz(r16 * DIM + kk * 32 + kgrp)]);
            #pragma unroll
            for (int t = 0; t < 8; ++t) {
                bf16x8 b = *reinterpret_cast<const bf16x8*>(wb2Tg + (size_t)(t * 16 + r16) * DIM + kk * 32 + kgrp);
                acc2[t] = __builtin_amdgcn_mfma_f32_16x16x32_bf16(a, b, acc2[t], 0, 0, 0);
            }
        }
        #pragma unroll
        for (int t = 0; t < 8; ++t) {
            int col = t * 16 + r16;
            #pragma unroll
            for (int r = 0; r < 4; r += 2) {
                int grow = row0 + wave * 16 + crow0 + r;
                float v0 = acc2[t][r]     + bias2[t];
                float v1 = acc2[t][r + 1] + bias2[t];
                resF[(size_t)grow * DIM + col]       = v0;
                resF[(size_t)(grow + 1) * DIM + col] = v1;
                unsigned int pk = cvtpk(v0, v1);
                resB[(size_t)grow * DIM + col]       = (unsigned short)pk;
                resB[(size_t)(grow + 1) * DIM + col] = (unsigned short)(pk >> 16);
            }
        }
    } else {
        int m = seg - 1;
        f32x4 acc2 = (f32x4){0.f, 0.f, 0.f, 0.f};
        #pragma unroll
        for (int kk = 0; kk < 4; ++kk) {
            bf16x8 a = *reinterpret_cast<const bf16x8*>(&hs[swz(r16 * DIM + kk * 32 + kgrp)]);
            bf16x8 b = *reinterpret_cast<const bf16x8*>(&W2fs[swz(r16 * DIM + kk * 32 + kgrp)]);
            acc2 = __builtin_amdgcn_mfma_f32_16x16x32_bf16(a, b, acc2, 0, 0, 0);
        }
        #pragma unroll
        for (int r = 0; r < 4; r += 2) {
            int grow = row0 + wave * 16 + crow0 + r;
            unsigned int pk = cvtpk(acc2[r] + bias2f, acc2[r + 1] + bias2f);
            Wallb[((size_t)m * NTOK + grow) * 16 + r16]     = (unsigned short)pk;
            Wallb[((size_t)m * NTOK + grow + 1) * 16 + r16] = (unsigned short)(pk >> 16);
        }
    }
}

// ---------------- kernel 3: ALL 12 scan steps — batched reads + W double-buffer ----------------
// sched_barrier-pinned 40-read batch + cross-step W register prefetch (7-dword rows).
// Numerics bit-identical: bf16 V carry (RNE cvtpk), bf16 res steps 0..10, f32 resF +
// f32 out at step 11, same ascending-k FMA chain.
// NOTE (r6/r15 evidence): the stride-4B ds_read_b32 gather is the ONLY conflict-free
// pattern for this kernel on gfx950 — b128 (16B/lane) and b64 (8B/lane) both produce
// millions of bank conflicts. Do not widen these reads.
#define CCH 2
#define RPAD 512
#define PADTOK (SEQ + RPAD)             // 4608 tokens incl ring pad
__global__ __launch_bounds__(1024) void scan_lds_kernel(
    const unsigned short* __restrict__ resB,
    const float* __restrict__ resF,
    const unsigned short* __restrict__ Wallb,   // [NM][NTOK][16]
    float* __restrict__ outF)
{
    __shared__ unsigned int V32[2 * PADTOK];    // 36 KB

    const int bid = (int)blockIdx.x;
    const int bb    = (bid >> 1) & 3;                 // batch -> XCD pair
    const int chunk = ((bid >> 3) << 1) | (bid & 1);  // 0..63
    const int d0  = chunk * CCH;
    const int tid = threadIdx.x;                      // 0..1023

    // ---- one-time: packed res regs + own-V regs (Bv) + seed V0 (with ring pad) ----
    unsigned int resP[4];
    unsigned int Bv[4];
    #pragma unroll
    for (int j = 0; j < 4; ++j) {
        int t = j * 1024 + tid;
        int n = (bb << 12) + t;
        unsigned int r = *reinterpret_cast<const unsigned int*>(resB + (size_t)n * DIM + d0);
        resP[j] = r;
        Bv[j] = r;
        V32[t] = r;
    }
    if (tid < RPAD) V32[SEQ + tid] = Bv[0];

    const unsigned short* wb0 = Wallb + (size_t)(bb << 12) * 16;

    // ---- preload W for step 0 (7 useful dwords per row: k = 0..12 -> w[k>>1]) ----
    unsigned int wA[4][7];
    #pragma unroll
    for (int j = 0; j < 4; ++j) {
        const unsigned int* wrow = reinterpret_cast<const unsigned int*>(wb0 + (size_t)(j * 1024 + tid) * 16);
        uint4 a = *reinterpret_cast<const uint4*>(wrow);
        uint2 b = *reinterpret_cast<const uint2*>(wrow + 4);
        unsigned int c = wrow[6];
        wA[j][0] = a.x; wA[j][1] = a.y; wA[j][2] = a.z; wA[j][3] = a.w;
        wA[j][4] = b.x; wA[j][5] = b.y; wA[j][6] = c;
    }
    __syncthreads();

    unsigned int curbase = 0;

    // ---- steps 0..10: bf16 V carry ----
    #pragma unroll 1
    for (int m = 0; m < NM - 1; ++m) {
        // batch ALL 40 LDS tap reads, issued in consumption (q-major) order
        unsigned int vt[4][10];
        #pragma unroll
        for (int q = 0; q < 10; ++q) {
            #pragma unroll
            for (int j = 0; j < 4; ++j)
                vt[j][q] = V32[curbase + j * 1024 + tid + (1 << q)];
        }
        // prefetch W for step m+1 (global, pinned L2) — consumed NEXT step
        unsigned int wN[4][7];
        {
            const unsigned short* wpn = wb0 + (size_t)(m + 1) * NTOK * 16;
            #pragma unroll
            for (int j = 0; j < 4; ++j) {
                const unsigned int* wrow = reinterpret_cast<const unsigned int*>(wpn + (size_t)(j * 1024 + tid) * 16);
                uint4 a = *reinterpret_cast<const uint4*>(wrow);
                uint2 b = *reinterpret_cast<const uint2*>(wrow + 4);
                unsigned int c = wrow[6];
                wN[j][0] = a.x; wN[j][1] = a.y; wN[j][2] = a.z; wN[j][3] = a.w;
                wN[j][4] = b.x; wN[j][5] = b.y; wN[j][6] = c;
            }
        }
        __builtin_amdgcn_sched_barrier(0);   // pin: no sinking reads into the FMA chain

        const unsigned int nb = curbase ^ PADTOK;
        float o0[4], o1[4];
        #pragma unroll
        for (int j = 0; j < 4; ++j) {
            o0[j] = uaf(resP[j] << 16);
            o1[j] = uaf(resP[j] & 0xffff0000u);
        }

        #pragma unroll
        for (int k = 0; k < NK; ++k) {
            #pragma unroll
            for (int j = 0; j < 4; ++j) {
                unsigned int ww = wA[j][k >> 1];
                float w = (k & 1) ? uaf(ww & 0xffff0000u) : uaf(ww << 16);
                unsigned int v;
                if (k == 0)       v = Bv[j];
                else if (k == 11) v = Bv[(j + 1) & 3];
                else if (k == 12) v = Bv[(j + 2) & 3];
                else              v = vt[j][k - 1];
                o0[j] = __builtin_fmaf(w, uaf(v << 16),          o0[j]);
                o1[j] = __builtin_fmaf(w, uaf(v & 0xffff0000u), o1[j]);
            }
        }

        #pragma unroll
        for (int j = 0; j < 4; ++j) {
            unsigned int pk = cvtpk(o0[j], o1[j]);
            Bv[j] = pk;
            V32[nb + j * 1024 + tid] = pk;
        }
        if (tid < RPAD) V32[nb + SEQ + tid] = Bv[0];

        // rotate prefetched W into place (vmcnt wait lands here, after compute)
        #pragma unroll
        for (int j = 0; j < 4; ++j)
            #pragma unroll
            for (int q = 0; q < 7; ++q)
                wA[j][q] = wN[j][q];
        __syncthreads();
        curbase = nb;
    }

    // ---- final step m=11: f32 res, f32 out; W already in wA ----
    {
        float2 rfv[4];
        #pragma unroll
        for (int j = 0; j < 4; ++j) {
            int n = (bb << 12) + j * 1024 + tid;
            rfv[j] = *reinterpret_cast<const float2*>(resF + (size_t)n * DIM + d0);
        }

        unsigned int vt[4][10];
        #pragma unroll
        for (int q = 0; q < 10; ++q) {
            #pragma unroll
            for (int j = 0; j < 4; ++j)
                vt[j][q] = V32[curbase + j * 1024 + tid + (1 << q)];
        }
        __builtin_amdgcn_sched_barrier(0);

        float o0[4], o1[4];
        #pragma unroll
        for (int j = 0; j < 4; ++j) { o0[j] = rfv[j].x; o1[j] = rfv[j].y; }

        #pragma unroll
        for (int k = 0; k < NK; ++k) {
            #pragma unroll
            for (int j = 0; j < 4; ++j) {
                unsigned int ww = wA[j][k >> 1];
                float w = (k & 1) ? uaf(ww & 0xffff0000u) : uaf(ww << 16);
                unsigned int v;
                if (k == 0)       v = Bv[j];
                else if (k == 11) v = Bv[(j + 1) & 3];
                else if (k == 12) v = Bv[(j + 2) & 3];
                else              v = vt[j][k - 1];
                o0[j] = __builtin_fmaf(w, uaf(v << 16),          o0[j]);
                o1[j] = __builtin_fmaf(w, uaf(v & 0xffff0000u), o1[j]);
            }
        }

        #pragma unroll
        for (int j = 0; j < 4; ++j) {
            int n = (bb << 12) + j * 1024 + tid;
            float2 o; o.x = o0[j]; o.y = o1[j];
            *reinterpret_cast<float2*>(outF + (size_t)n * DIM + d0) = o;
        }
    }
}

// ---------------- launch ----------------
extern "C" void kernel_launch(void* const* d_in, const int* in_sizes, int n_in,
                              void* d_out, int out_size, void* d_ws, size_t ws_size,
                              hipStream_t stream) {
    const int*   data = (const int*)  d_in[0];
    const float* emb  = (const float*)d_in[2];
    const float* apc  = (const float*)d_in[3];
    const float* g_W1 = (const float*)d_in[4];
    const float* g_b1 = (const float*)d_in[5];
    const float* g_W2 = (const float*)d_in[6];
    const float* g_b2 = (const float*)d_in[7];
    const float* f_W1 = (const float*)d_in[8];
    const float* f_b1 = (const float*)d_in[9];
    const float* f_W2 = (const float*)d_in[10];
    const float* f_b2 = (const float*)d_in[11];
    float* out = (float*)d_out;

    char* ws = (char*)d_ws;
    size_t off = 0;
    auto alloc = [&](size_t bytes) {
        void* p = ws + off;
        off += (bytes + 255) & ~(size_t)255;
        return p;
    };
    unsigned short* xb    = (unsigned short*)alloc((size_t)NTOK * DIM * 2);
    unsigned short* wb1T  = (unsigned short*)alloc((size_t)NSEG * DIM * DIM * 2);
    unsigned short* wb2Tg = (unsigned short*)alloc((size_t)DIM * DIM * 2);
    unsigned short* wb2Tf = (unsigned short*)alloc((size_t)NM * 16 * DIM * 2);
    float*          resF  = (float*)alloc((size_t)NTOK * DIM * 4);
    unsigned short* resB  = (unsigned short*)alloc((size_t)NTOK * DIM * 2);
    unsigned short* Wallb = (unsigned short*)alloc((size_t)NM * NTOK * 16 * 2);
    (void)ws_size; (void)in_sizes; (void)n_in; (void)out_size;

    prep_kernel<<<EMB_BLOCKS + CONV_BLOCKS, 256, 0, stream>>>(
        data, emb, apc, xb, g_W1, g_W2, f_W1, f_W2, wb1T, wb2Tg, wb2Tf);

    dim3 grid(NTOK / 64, NSEG);
    mlp_kernel<<<grid, 256, 0, stream>>>(xb, wb1T, wb2Tg, wb2Tf,
                                         g_b1, g_b2, f_b1, f_b2, resF, resB, Wallb);

    // all 12 scan steps in one kernel (r11/r14 proven config): sched_barrier-pinned batched
    // LDS reads, cross-step W register double-buffer (7-dword rows), batch->XCD pinned
    scan_lds_kernel<<<256, 1024, 0, stream>>>(resB, resF, Wallb, out);
}